// Round 1
// 449.981 us; speedup vs baseline: 1.0561x; 1.0561x over previous
//
#include <hip/hip_runtime.h>

// ---------------------------------------------------------------------------
// MambaLayer on MI355X (gfx950).
// Pipeline (all f16 MFMA with fp32 accumulate; scan/elementwise in fp32):
//   1. convert x -> f16; transpose-convert W_in, W_out -> N-major f16 (B^T form)
//   2. GEMM1: xr = x @ W_in          (16384x4096x1024)
//   3. conv_bc_fin: conv(3)+SiLU -> xc  AND  BtCt = xc @ [W_B|W_C] (MFMA,
//      per-wave K-split, no main-loop barriers) AND per-chunk fin states
//   4. scan_p2: carry propagation across chunks (tiny)
//   5. scan_p3_fuse: replay chunk scan (reg-preloaded) -> ys in LDS, then
//      y = (ys + xc*D) * silu(res) -> overwrite xc (f16)
//   6. GEMM2: out = y @ W_out        (16384x1024x2048), fp32 out
//
// R1: gemm_tn: BK 32->64 + XOR-swizzled LDS (conflicts 1.68e7 -> 0)
// R2: scan restructured to 3 wide phases; p3 fused with y-fuse elementwise.
// R3: FAILED (+34us): VALU-dot fusion — bc off MFMA pipe + broadcast loads.
// R4: chunked conv, bc split-K=2, p3 reg-preload. 508us.
// R5: conv+bc+p1 fused KEEPING MFMA. 475us. GEMMs = 3x ~110us at 625 TF,
//     MfmaUtil 26%: 2-barrier loop drains vmcnt(0) every K-step.
// R6: gemm256 — 256x256 tile, BK=64, 8 waves (2x4), 8-phase schedule with
//     counted vmcnt (never 0 in steady state): per K-tile 4 quadrant phases
//     {ds_read 12/4 b128; stage 1 half-tile (2x global_load_lds 16B);
//      s_barrier; lgkmcnt(0); setprio(1); 16 MFMA; setprio(0); s_barrier}.
//     Stage ring runs 6 halves ahead; one vmcnt(4) gate per K-tile.
//     Slot-rewrite is always >=1 barrier after last read (race-free by
//     construction). XCD-chunked block swizzle: each XCD owns 8 A-row-panels.
// ---------------------------------------------------------------------------

typedef _Float16 half8 __attribute__((ext_vector_type(8)));
typedef float floatx4 __attribute__((ext_vector_type(4)));

#define D_MODEL 1024
#define D_INNER 2048
#define SEQ     4096
#define NBATCH  4
#define NROWS   (NBATCH * SEQ)        // 16384
#define CHUNK   16
#define NCHUNK  (SEQ / CHUNK)         // 256 chunks per batch
#define NTASK   (NBATCH * NCHUNK)     // 1024 chunk-tasks

__device__ __forceinline__ void async16(_Float16* lds, const _Float16* g) {
    // global -> LDS direct copy, 16B per lane; LDS dest = wave-uniform base + lane*16
    __builtin_amdgcn_global_load_lds((const __attribute__((address_space(1))) void*)g,
                                     (__attribute__((address_space(3))) void*)lds, 16, 0, 0);
}

__device__ __forceinline__ float siluf(float x) {
    return x / (1.f + __expf(-x));
}

__device__ __forceinline__ float decay_of(const float* A, int s) {
    return __expf(-log1pf(__expf(A[s])));   // exp(-softplus(A[s]))
}

// --------------------------- conversion kernels ----------------------------

__global__ __launch_bounds__(256) void convert_f32_f16(const float* __restrict__ src,
                                                       _Float16* __restrict__ dst) {
    size_t idx = ((size_t)blockIdx.x * 256 + threadIdx.x) * 8;
    float4 a = *(const float4*)(src + idx);
    float4 b = *(const float4*)(src + idx + 4);
    half8 o = {(_Float16)a.x, (_Float16)a.y, (_Float16)a.z, (_Float16)a.w,
               (_Float16)b.x, (_Float16)b.y, (_Float16)b.z, (_Float16)b.w};
    *(half8*)(dst + idx) = o;
}

// src: K x N fp32 (row-major), dst: N x K f16 (row-major)  [i.e. B^T]
__global__ __launch_bounds__(256) void transpose_to_f16(const float* __restrict__ src,
                                                        _Float16* __restrict__ dst,
                                                        int K, int N) {
    __shared__ float tile[32][33];
    int n0 = blockIdx.x * 32, k0 = blockIdx.y * 32;
    int x = threadIdx.x, y = threadIdx.y;   // 32 x 8
#pragma unroll
    for (int r = 0; r < 32; r += 8)
        tile[y + r][x] = src[(size_t)(k0 + y + r) * N + (n0 + x)];
    __syncthreads();
#pragma unroll
    for (int r = 0; r < 32; r += 8)
        dst[(size_t)(n0 + y + r) * K + (k0 + x)] = (_Float16)tile[x][y + r];
}

// WBCT[n][k], n<16 -> W_B[:,n], n>=16 -> W_C[:,n-16]; shape 32 x 2048 f16
__global__ __launch_bounds__(256) void convert_wbct(const float* __restrict__ WB,
                                                    const float* __restrict__ WC,
                                                    _Float16* __restrict__ WBCT) {
    int idx = blockIdx.x * 256 + threadIdx.x;   // 0 .. 65535
    int n = idx >> 11, k = idx & 2047;
    float v = (n < 16) ? WB[k * 16 + n] : WC[k * 16 + (n - 16)];
    WBCT[idx] = (_Float16)v;
}

// ------------------------------- main GEMM ---------------------------------
// C(MxN) = A(MxK) * B(KxN), B given as BT (NxK row-major). f16 in, fp32 acc.
// 256x256 tile, BK=64, 512 threads = 8 waves (wm 0..1, wn 0..3); per-wave
// output 128x64 = 8x4 fragments of 16x16. LDS 128 KiB: A/B double-buffered
// at K-tile granularity, each buffer 256x64 f16 split in 2 halves of 128 rows.
// 16B-chunk XOR swizzle: chunk c of row r stored at position c ^ (r&7)
// (staging permutes the GLOBAL source column; LDS dest stays linear because
// global_load_lds writes base+lane*16).
//
// Schedule per K-tile t (4 phases, quadrant (mq,nq) = rows mq*128+wm*64,
// cols nq*128+wn*32):
//   p0 (0,0): read A(mq0) 8 + B(nq0) 4 b128; stage A-h1 of t+1 (buf^1)
//   p1 (0,1): read B(nq1) 4;                 stage B-h1 of t+1 (buf^1)
//   p2 (1,0): read A(mq1) 8 + B(nq0) 4;      stage A-h0 of t+2 (buf)
//   p3 (1,1): read B(nq1) 4;                 stage B-h0 of t+2 (buf);
//             s_waitcnt vmcnt(4)  [tile t+1 fully landed, 2 halves in flight]
// Each phase: barrier; lgkmcnt(0); setprio(1); 16 MFMA; setprio(0); barrier.
// Every slot rewrite issues >=1 barrier after that slot's last read:
//   A-h0 last read p1 / restaged p2;  B-h0 last read p2 / restaged p3;
//   A-h1 last read p3 / restaged p0 of t+1;  B-h1 p3 / p1 of t+1.

__device__ __forceinline__ void stage_half(const _Float16* __restrict__ src, int K,
                                           int rowBase, int k0, _Float16* ldsHalf) {
    const int tid = threadIdx.x;
    const int sr = tid >> 3, wid = tid >> 6;
    const int lc = ((tid & 7) ^ (sr & 7)) << 3;     // swizzled source col (elems)
#pragma unroll
    for (int r = 0; r < 2; r++) {
        const _Float16* g = src + (size_t)(rowBase + r * 64 + sr) * K + (k0 + lc);
        async16(ldsHalf + r * 4096 + wid * 512, g);
    }
}

#define GP_LOAD(MQ, NQ, LOADA)                                                          \
    if (LOADA) {                                                                        \
        _Pragma("unroll") for (int m = 0; m < 4; m++) {                                 \
            const int lr = (MQ) * 128 + wm * 64 + m * 16 + fr;                          \
            _Pragma("unroll") for (int s = 0; s < 2; s++)                               \
                af[m][s] = *(const half8*)(Ab + lr * 64 + ((((s << 2) + q) ^ frq) << 3)); \
        }                                                                               \
    }                                                                                   \
    {                                                                                   \
        _Pragma("unroll") for (int n = 0; n < 2; n++) {                                 \
            const int br = (NQ) * 128 + wn * 32 + n * 16 + fr;                          \
            _Pragma("unroll") for (int s = 0; s < 2; s++)                               \
                bf[n][s] = *(const half8*)(Bb + br * 64 + ((((s << 2) + q) ^ frq) << 3)); \
        }                                                                               \
    }

#define GP_MMA(MQ, NQ)                                                                  \
    __builtin_amdgcn_s_barrier();                                                       \
    asm volatile("s_waitcnt lgkmcnt(0)" ::: "memory");                                  \
    __builtin_amdgcn_s_setprio(1);                                                      \
    _Pragma("unroll") for (int m = 0; m < 4; m++)                                       \
        _Pragma("unroll") for (int n = 0; n < 2; n++)                                   \
            _Pragma("unroll") for (int s = 0; s < 2; s++)                               \
                acc[(MQ) * 4 + m][(NQ) * 2 + n] = __builtin_amdgcn_mfma_f32_16x16x32_f16( \
                    af[m][s], bf[n][s], acc[(MQ) * 4 + m][(NQ) * 2 + n], 0, 0, 0);      \
    __builtin_amdgcn_s_setprio(0);                                                      \
    __builtin_amdgcn_s_barrier();

template <typename OutT>
__global__ __launch_bounds__(512, 2) void gemm256(const _Float16* __restrict__ A,
                                                  const _Float16* __restrict__ BT,
                                                  OutT* __restrict__ C,
                                                  int M, int N, int K) {
    __shared__ __align__(16) _Float16 smem[4 * 16384];   // 128 KiB: A0,A1,B0,B1
    _Float16* const AsBase = smem;
    _Float16* const BsBase = smem + 32768;

    const int tid = threadIdx.x;
    const int wid = tid >> 6, lane = tid & 63;
    const int wm = wid >> 2, wn = wid & 3;               // 2 x 4 waves
    const int fr = lane & 15, q = lane >> 4, frq = fr & 7;

    // XCD-chunked bijective swizzle: dispatch slot lin runs on XCD lin%8;
    // give each XCD a contiguous range of logical ids -> 8 full A-row-panels.
    int lin = blockIdx.y * gridDim.x + blockIdx.x;
    const int nwg = gridDim.x * gridDim.y;               // multiple of 8 here
    lin = (lin & 7) * (nwg >> 3) + (lin >> 3);
    const int bx = lin % gridDim.x, by = lin / gridDim.x;
    const int row0 = by * 256, col0 = bx * 256;
    const int NT = K >> 6;

    floatx4 acc[8][4] = {};
    half8 af[4][2], bf[2][2];

    // Prologue: tile0 fully + tile1 {A-h0, B-h0}; gate leaves tile1 halves in flight.
    stage_half(A,  K, row0,       0, AsBase);            // t0 A-h0
    stage_half(BT, K, col0,       0, BsBase);            // t0 B-h0
    stage_half(A,  K, row0 + 128, 0, AsBase + 8192);     // t0 A-h1
    stage_half(BT, K, col0 + 128, 0, BsBase + 8192);     // t0 B-h1
    if (NT > 1) {
        stage_half(A,  K, row0, 64, AsBase + 16384);     // t1 A-h0
        stage_half(BT, K, col0, 64, BsBase + 16384);     // t1 B-h0
        asm volatile("s_waitcnt vmcnt(4)" ::: "memory");
    } else {
        asm volatile("s_waitcnt vmcnt(0)" ::: "memory");
    }
    __builtin_amdgcn_s_barrier();

    for (int t = 0; t < NT; ++t) {
        _Float16* Ab  = AsBase + ((t & 1) << 14);
        _Float16* Bb  = BsBase + ((t & 1) << 14);
        _Float16* Abn = AsBase + (((t + 1) & 1) << 14);
        _Float16* Bbn = BsBase + (((t + 1) & 1) << 14);
        const int k1 = (t + 1) << 6, k2 = (t + 2) << 6;
        const bool s1 = (t + 1) < NT, s2 = (t + 2) < NT;

        GP_LOAD(0, 0, 1);
        if (s1) stage_half(A, K, row0 + 128, k1, Abn + 8192);
        GP_MMA(0, 0);

        GP_LOAD(0, 1, 0);
        if (s1) stage_half(BT, K, col0 + 128, k1, Bbn + 8192);
        GP_MMA(0, 1);

        GP_LOAD(1, 0, 1);
        if (s2) stage_half(A, K, row0, k2, Ab);
        GP_MMA(1, 0);

        GP_LOAD(1, 1, 0);
        if (s2) stage_half(BT, K, col0, k2, Bb);
        if (s2) {
            asm volatile("s_waitcnt vmcnt(4)" ::: "memory");
        } else if (t + 2 == NT) {
            asm volatile("s_waitcnt vmcnt(0)" ::: "memory");
        }
        GP_MMA(1, 1);
    }

    // C/D layout: col = lane&15, row = (lane>>4)*4 + reg   [measured m89/m91]
    const int er = (lane >> 4) * 4, ec = lane & 15;
#pragma unroll
    for (int fi = 0; fi < 8; fi++)
#pragma unroll
        for (int fj = 0; fj < 4; fj++)
#pragma unroll
            for (int r = 0; r < 4; r++) {
                int row = row0 + (fi >> 2) * 128 + wm * 64 + (fi & 3) * 16 + er + r;
                int col = col0 + (fj >> 1) * 128 + wn * 32 + (fj & 1) * 16 + ec;
                C[(size_t)row * N + col] = (OutT)acc[fi][fj][r];
            }
}

// ---------------- fused conv + silu + Bt/Ct (MFMA) + scan p1 ----------------
// Block = 32 rows (2 chunks), 256 threads = 4 waves. Waves own disjoint K
// quarters (512 cols = 4 panels of 128) -> NO barriers in the main loop.
__global__ __launch_bounds__(256) void conv_bc_fin(const _Float16* __restrict__ xr,
                                                   const float* __restrict__ cw,
                                                   const float* __restrict__ cb,
                                                   const _Float16* __restrict__ WBCT,
                                                   const float* __restrict__ A,
                                                   _Float16* __restrict__ xc,
                                                   float* __restrict__ BtCt,
                                                   float* __restrict__ fin) {
    __shared__ __align__(16) _Float16 As[4 * 32 * 128];   // 32 KB; reused in epilogue
    const int tid = threadIdx.x, wid = tid >> 6, lane = tid & 63;
    const int row0 = blockIdx.x * 32;
    const int l0 = row0 & (SEQ - 1);
    const int cg = lane & 15;            // col-group within panel (8 cols)
    const int rg = lane >> 4;            // row-group (8 rows)
    const int fr = lane & 15, q = lane >> 4;
    _Float16* As_w = As + wid * 4096;
    const int r0 = rg * 8;

    floatx4 acc[2][2] = {};

    for (int t = 0; t < 4; t++) {
        const int kbase = wid * 512 + t * 128;
        const int gcol = kbase + cg * 8;
        float w0[8], w1[8], w2[8], bb[8];
#pragma unroll
        for (int j = 0; j < 8; j++) {
            w0[j] = cw[(gcol + j) * 3];
            w1[j] = cw[(gcol + j) * 3 + 1];
            w2[j] = cw[(gcol + j) * 3 + 2];
            bb[j] = cb[gcol + j];
        }
        half8 prev = {}, cur, nxt;
        if (!(l0 == 0 && rg == 0))
            prev = *(const half8*)(xr + (size_t)(row0 + r0 - 1) * 4096 + gcol);
        cur = *(const half8*)(xr + (size_t)(row0 + r0) * 4096 + gcol);
#pragma unroll
        for (int r = 0; r < 8; r++) {
            if (r == 7 && rg == 3 && l0 + 32 == SEQ) {
                half8 z = {};
                nxt = z;
            } else {
                nxt = *(const half8*)(xr + (size_t)(row0 + r0 + r + 1) * 4096 + gcol);
            }
            half8 o;
#pragma unroll
            for (int j = 0; j < 8; j++) {
                float a = (float)prev[j] * w0[j] + (float)cur[j] * w1[j] +
                          (float)nxt[j] * w2[j] + bb[j];
                o[j] = (_Float16)siluf(a);
            }
            const int lrow = r0 + r;
            *(half8*)(xc + (size_t)(row0 + lrow) * D_INNER + gcol) = o;
            *(half8*)(As_w + lrow * 128 + ((cg ^ (lrow & 7)) * 8)) = o;
            prev = cur;
            cur = nxt;
        }
#pragma unroll
        for (int ks = 0; ks < 4; ks++) {
            half8 af[2], bf[2];
#pragma unroll
            for (int rt = 0; rt < 2; rt++)
                af[rt] = *(const half8*)(As_w + (rt * 16 + fr) * 128 +
                                         (((ks * 4 + q) ^ (fr & 7)) * 8));
#pragma unroll
            for (int ot = 0; ot < 2; ot++)
                bf[ot] = *(const half8*)(WBCT + (size_t)(ot * 16 + fr) * D_INNER +
                                         kbase + ks * 32 + q * 8);
#pragma unroll
            for (int rt = 0; rt < 2; rt++)
#pragma unroll
                for (int ot = 0; ot < 2; ot++)
                    acc[rt][ot] = __builtin_amdgcn_mfma_f32_16x16x32_f16(af[rt], bf[ot], acc[rt][ot], 0, 0, 0);
        }
    }

    __syncthreads();                       // all waves done reading As as f16
    float* red = (float*)As;               // [wid][row 32][out 32] = 4096 f32 (16 KB)
    float* btl = (float*)As + 4096;        // [row 32][out 32] = 1024 f32 (4 KB)
    const int er = (lane >> 4) * 4, ec = lane & 15;
#pragma unroll
    for (int rt = 0; rt < 2; rt++)
#pragma unroll
        for (int ot = 0; ot < 2; ot++)
#pragma unroll
            for (int rr = 0; rr < 4; rr++)
                red[wid * 1024 + (rt * 16 + er + rr) * 32 + ot * 16 + ec] = acc[rt][ot][rr];
    __syncthreads();
#pragma unroll
    for (int i = 0; i < 4; i++) {
        int idx = i * 256 + tid;           // (row<<5)|out
        float v = red[idx] + red[1024 + idx] + red[2048 + idx] + red[3072 + idx];
        btl[idx] = v;
        BtCt[(size_t)row0 * 32 + idx] = v; // (row0+row)*32+out == row0*32+idx
    }
    __syncthreads();
    if (tid < 32) {                        // 2 chunks x 16 states
        const int ch = tid >> 4, s = tid & 15;
        const float decay = decay_of(A, s);
        float st = 0.f;
#pragma unroll
        for (int r = 0; r < CHUNK; r++)
            st = st * decay + btl[(ch * 16 + r) * 32 + s];
        fin[((row0 >> 4) + ch) * 16 + s] = st;
    }
}

// -------------------------------- scan -------------------------------------
// phase 2: carry propagation across chunks. 1 block x 64 threads (b,s).
__global__ __launch_bounds__(64) void scan_p2(const float* __restrict__ fin,
                                              const float* __restrict__ A,
                                              float* __restrict__ carry) {
    int t = threadIdx.x;
    int b = t >> 4, s = t & 15;
    float decay = decay_of(A, s);
    float d16 = decay;
#pragma unroll
    for (int k = 0; k < 4; k++) d16 *= d16;     // decay^16
    float cy = 0.f;
#pragma unroll 8
    for (int c = 0; c < NCHUNK; c++) {
        int idx = ((b * NCHUNK) + c) * 16 + s;
        carry[idx] = cy;
        cy = cy * d16 + fin[idx];
    }
}

// phase 3 + y-fuse: replay chunk scan (lanes 0..15, Bt/Ct preloaded to regs)
// -> ys in LDS, then all 256 threads compute y = (ys + xc*D) * silu(res),
// overwriting xc (f16). 1024 blocks x 256 threads; block = chunk-task.
__global__ __launch_bounds__(256) void scan_p3_fuse(const float* __restrict__ BtCt,
                                                    const float* __restrict__ A,
                                                    const float* __restrict__ carry,
                                                    const float* __restrict__ D,
                                                    const _Float16* __restrict__ xr,
                                                    _Float16* __restrict__ xc) {
    __shared__ float ysl[CHUNK];
    const int task = blockIdx.x;
    const int b = task >> 8, c = task & (NCHUNK - 1);
    const int row0 = b * SEQ + c * CHUNK;
    const int tid = threadIdx.x;

    if (tid < 16) {
        const int s = tid;
        const float decay = decay_of(A, s);
        size_t r = (size_t)row0 * 32;
        float bt[CHUNK], ct[CHUNK];
#pragma unroll
        for (int j = 0; j < CHUNK; j++) {       // independent loads, ILP
            bt[j] = BtCt[r + (size_t)j * 32 + s];
            ct[j] = BtCt[r + (size_t)j * 32 + 16 + s];
        }
        float st = carry[task * 16 + s];
        float yv[CHUNK];
#pragma unroll
        for (int j = 0; j < CHUNK; j++) {       // serial FMA chain only
            st = st * decay + bt[j];
            yv[j] = st * ct[j];
        }
#pragma unroll
        for (int j = 0; j < CHUNK; j++) {       // 16 independent reduce chains
            float y = yv[j];
            y += __shfl_xor(y, 1, 16);
            y += __shfl_xor(y, 2, 16);
            y += __shfl_xor(y, 4, 16);
            y += __shfl_xor(y, 8, 16);
            if (s == 0) ysl[j] = y;
        }
    }
    __syncthreads();

#pragma unroll
    for (int it = 0; it < 16; it++) {
        int chunk = it * 256 + tid;            // 0..4095 (16 rows x 256 col-chunks)
        int rl = chunk >> 8;                   // row within chunk
        int colb = (chunk & 255) * 8;          // col offset (elements)
        size_t row = (size_t)(row0 + rl);
        float yv = ysl[rl];
        half8 x8 = *(const half8*)(xc + row * D_INNER + colb);
        half8 r8 = *(const half8*)(xr + row * 4096 + 2048 + colb);
        float4 d0 = *(const float4*)(D + colb);
        float4 d1 = *(const float4*)(D + colb + 4);
        half8 o;
        float dd[8] = {d0.x, d0.y, d0.z, d0.w, d1.x, d1.y, d1.z, d1.w};
#pragma unroll
        for (int j = 0; j < 8; j++) {
            float y = yv + (float)x8[j] * dd[j];
            o[j] = (_Float16)(y * siluf((float)r8[j]));
        }
        *(half8*)(xc + row * D_INNER + colb) = o;
    }
}

// ------------------------------- launcher ----------------------------------
extern "C" void kernel_launch(void* const* d_in, const int* in_sizes, int n_in,
                              void* d_out, int out_size, void* d_ws, size_t ws_size,
                              hipStream_t stream) {
    const float* x      = (const float*)d_in[0];
    const float* W_in   = (const float*)d_in[1];
    const float* conv_w = (const float*)d_in[2];
    const float* conv_b = (const float*)d_in[3];
    const float* W_B    = (const float*)d_in[4];
    const float* W_C    = (const float*)d_in[5];
    const float* A      = (const float*)d_in[6];
    const float* D      = (const float*)d_in[7];
    const float* W_out  = (const float*)d_in[8];
    float* out = (float*)d_out;

    char* ws = (char*)d_ws;
    size_t off = 0;
    auto alloc = [&](size_t bytes) { size_t o = off; off += (bytes + 255) & ~(size_t)255; return o; };
    _Float16* xh    = (_Float16*)(ws + alloc((size_t)NROWS * D_MODEL * 2));      // 33.5 MB
    _Float16* WinT  = (_Float16*)(ws + alloc((size_t)4096 * 1024 * 2));          //  8.4 MB
    _Float16* WoutT = (_Float16*)(ws + alloc((size_t)1024 * 2048 * 2));          //  4.2 MB
    _Float16* WBCT  = (_Float16*)(ws + alloc((size_t)32 * 2048 * 2));            //  0.13 MB
    _Float16* xr    = (_Float16*)(ws + alloc((size_t)NROWS * 4096 * 2));         //  134 MB
    _Float16* xc    = (_Float16*)(ws + alloc((size_t)NROWS * D_INNER * 2));      //   67 MB
    float*    BtCt  = (float*)(ws + alloc((size_t)NROWS * 32 * 4));              //    2 MB
    float*    fin   = (float*)(ws + alloc((size_t)NTASK * 16 * 4));              //  64 KB
    float*    carry = (float*)(ws + alloc((size_t)NTASK * 16 * 4));              //  64 KB

    // 1. conversions
    convert_f32_f16<<<(NROWS * D_MODEL) / (256 * 8), 256, 0, stream>>>(x, xh);
    transpose_to_f16<<<dim3(4096 / 32, 1024 / 32), dim3(32, 8), 0, stream>>>(W_in, WinT, 1024, 4096);
    transpose_to_f16<<<dim3(1024 / 32, 2048 / 32), dim3(32, 8), 0, stream>>>(W_out, WoutT, 2048, 1024);
    convert_wbct<<<(32 * 2048) / 256, 256, 0, stream>>>(W_B, W_C, WBCT);
    // 2. GEMM1: xr = x @ W_in   (16384x4096x1024), 8-phase 256^2
    gemm256<_Float16><<<dim3(4096 / 256, NROWS / 256), 512, 0, stream>>>(xh, WinT, xr, NROWS, 4096, 1024);
    // 3. conv + silu + Bt/Ct + fin (fused, MFMA)
    conv_bc_fin<<<NROWS / 32, 256, 0, stream>>>(xr, conv_w, conv_b, WBCT, A, xc, BtCt, fin);
    // 4. scan phase 2
    scan_p2<<<1, 64, 0, stream>>>(fin, A, carry);
    // 5. scan phase 3 + y-fuse
    scan_p3_fuse<<<NTASK, 256, 0, stream>>>(BtCt, A, carry, D, xr, xc);
    // 6. GEMM2: out = y @ W_out (16384x1024x2048), 8-phase 256^2
    gemm256<float><<<dim3(1024 / 256, NROWS / 256), 512, 0, stream>>>(xc, WoutT, out, NROWS, 1024, 2048);
}

// Round 3
// 436.972 us; speedup vs baseline: 1.0875x; 1.0298x over previous
//
#include <hip/hip_runtime.h>

// ---------------------------------------------------------------------------
// MambaLayer on MI355X (gfx950).
// Pipeline (all f16 MFMA with fp32 accumulate; scan/elementwise in fp32):
//   1. convert x -> f16; transpose-convert W_in, W_out -> N-major f16 (B^T form)
//   2. GEMM1: xr = x @ W_in          (16384x4096x1024)
//   3. conv_bc_fin: conv(3)+SiLU -> xc  AND  BtCt = xc @ [W_B|W_C] (MFMA,
//      per-wave K-split, no main-loop barriers) AND per-chunk fin states
//   4. scan_p2: carry propagation across chunks (tiny)
//   5. scan_p3_fuse: replay chunk scan (reg-preloaded) -> ys in LDS, then
//      y = (ys + xc*D) * silu(res) -> overwrite xc (f16)
//   6. GEMM2: out = y @ W_out        (16384x1024x2048), fp32 out
//
// R5: conv+bc+p1 fused KEEPING MFMA. 475us. GEMMs ~3x110us @ 625 TF.
// R6: gemm256 8-phase 256^2 BK=64 counted-vmcnt. 450us. GEMM1 157.7us
//     (871 TF, MfmaUtil 37%); per-K-tile 5914 cyc vs m201 template 3295:
//     reads consumed in-phase -> per-phase [read-drain]->[MFMA] serialize.
// R7: half-pipelined reads within the 256-reg cap:
//     - B-dedup: bf0/bf1 both live (+16 VGPR, 24 reads/tile not 32)
//     - bf0 of tile t+1 read at p3(t) AFTER gate + extra barrier (all-wave
//       landing guarantee); bf1 read at p0 hidden under q00's MFMA; only
//       the two af loads (8+8) remain in-phase.
//     - dropped explicit lgkmcnt(0): compiler emits counted waits from
//       dataflow, which now is the desired pipeline.
//     Slot coverage re-verified: every LDS read preceded by [every-wave
//     vmcnt gate covering that slot] + [barrier]; rewrites >=2 barriers
//     after last consumption.
// R8: resubmit of R7 — round-2 container failure diagnosed as infra
//     (timing block showed 556s npz push; no kernel-side hang vector:
//     barriers uniform, WAR coverage verified, no OOB, LDS 128KiB).
// ---------------------------------------------------------------------------

typedef _Float16 half8 __attribute__((ext_vector_type(8)));
typedef float floatx4 __attribute__((ext_vector_type(4)));

#define D_MODEL 1024
#define D_INNER 2048
#define SEQ     4096
#define NBATCH  4
#define NROWS   (NBATCH * SEQ)        // 16384
#define CHUNK   16
#define NCHUNK  (SEQ / CHUNK)         // 256 chunks per batch
#define NTASK   (NBATCH * NCHUNK)     // 1024 chunk-tasks

__device__ __forceinline__ void async16(_Float16* lds, const _Float16* g) {
    // global -> LDS direct copy, 16B per lane; LDS dest = wave-uniform base + lane*16
    __builtin_amdgcn_global_load_lds((const __attribute__((address_space(1))) void*)g,
                                     (__attribute__((address_space(3))) void*)lds, 16, 0, 0);
}

__device__ __forceinline__ float siluf(float x) {
    return x / (1.f + __expf(-x));
}

__device__ __forceinline__ float decay_of(const float* A, int s) {
    return __expf(-log1pf(__expf(A[s])));   // exp(-softplus(A[s]))
}

// --------------------------- conversion kernels ----------------------------

__global__ __launch_bounds__(256) void convert_f32_f16(const float* __restrict__ src,
                                                       _Float16* __restrict__ dst) {
    size_t idx = ((size_t)blockIdx.x * 256 + threadIdx.x) * 8;
    float4 a = *(const float4*)(src + idx);
    float4 b = *(const float4*)(src + idx + 4);
    half8 o = {(_Float16)a.x, (_Float16)a.y, (_Float16)a.z, (_Float16)a.w,
               (_Float16)b.x, (_Float16)b.y, (_Float16)b.z, (_Float16)b.w};
    *(half8*)(dst + idx) = o;
}

// src: K x N fp32 (row-major), dst: N x K f16 (row-major)  [i.e. B^T]
__global__ __launch_bounds__(256) void transpose_to_f16(const float* __restrict__ src,
                                                        _Float16* __restrict__ dst,
                                                        int K, int N) {
    __shared__ float tile[32][33];
    int n0 = blockIdx.x * 32, k0 = blockIdx.y * 32;
    int x = threadIdx.x, y = threadIdx.y;   // 32 x 8
#pragma unroll
    for (int r = 0; r < 32; r += 8)
        tile[y + r][x] = src[(size_t)(k0 + y + r) * N + (n0 + x)];
    __syncthreads();
#pragma unroll
    for (int r = 0; r < 32; r += 8)
        dst[(size_t)(n0 + y + r) * K + (k0 + x)] = (_Float16)tile[x][y + r];
}

// WBCT[n][k], n<16 -> W_B[:,n], n>=16 -> W_C[:,n-16]; shape 32 x 2048 f16
__global__ __launch_bounds__(256) void convert_wbct(const float* __restrict__ WB,
                                                    const float* __restrict__ WC,
                                                    _Float16* __restrict__ WBCT) {
    int idx = blockIdx.x * 256 + threadIdx.x;   // 0 .. 65535
    int n = idx >> 11, k = idx & 2047;
    float v = (n < 16) ? WB[k * 16 + n] : WC[k * 16 + (n - 16)];
    WBCT[idx] = (_Float16)v;
}

// ------------------------------- main GEMM ---------------------------------
// C(MxN) = A(MxK) * B(KxN), B given as BT (NxK row-major). f16 in, fp32 acc.
// 256x256 tile, BK=64, 512 threads = 8 waves (wm 0..1, wn 0..3); per-wave
// output 128x64 = 8x4 fragments of 16x16. LDS 128 KiB: A/B double-buffered
// at K-tile granularity, each buffer 256x64 f16 split in 2 halves of 128 rows.
// 16B-chunk XOR swizzle: chunk c of row r stored at position c ^ (r&7)
// (staging permutes the GLOBAL source column; LDS dest stays linear because
// global_load_lds writes base+lane*16).
//
// Stage ring (per K-tile t): p0: Ah1(t+1); p1: Bh1(t+1); p2: Ah0(t+2);
// p3: Bh0(t+2), then gate vmcnt(4) (tile t+1 fully landed, 2 halves in
// flight), extra barrier, then read bf0(t+1) for next tile's q00.
// Read schedule: p0: af(mq0)[8, in-phase] + bf1(nq1)[4, for p1];
// p1: none; p2: af(mq1)[8, in-phase]; p3: bf0' [4, post-gate+barrier].
// Each MMA phase: barrier; setprio(1); 16 MFMA; setprio(0); barrier
// (compiler inserts minimal counted lgkm waits from dataflow).

__device__ __forceinline__ void stage_half(const _Float16* __restrict__ src, int K,
                                           int rowBase, int k0, _Float16* ldsHalf) {
    const int tid = threadIdx.x;
    const int sr = tid >> 3, wid = tid >> 6;
    const int lc = ((tid & 7) ^ (sr & 7)) << 3;     // swizzled source col (elements)
#pragma unroll
    for (int r = 0; r < 2; r++) {
        const _Float16* g = src + (size_t)(rowBase + r * 64 + sr) * K + (k0 + lc);
        async16(ldsHalf + r * 4096 + wid * 512, g);
    }
}

__device__ __forceinline__ void loadA8(half8 af[4][2], const _Float16* Ab, int base,
                                       int sw0, int sw1) {
#pragma unroll
    for (int m = 0; m < 4; m++) {
        const _Float16* p = Ab + base + m * 1024;   // +16 rows per m
        af[m][0] = *(const half8*)(p + sw0);
        af[m][1] = *(const half8*)(p + sw1);
    }
}

__device__ __forceinline__ void loadB4(half8 bf[2][2], const _Float16* Bb, int base,
                                       int sw0, int sw1) {
#pragma unroll
    for (int n = 0; n < 2; n++) {
        const _Float16* p = Bb + base + n * 1024;
        bf[n][0] = *(const half8*)(p + sw0);
        bf[n][1] = *(const half8*)(p + sw1);
    }
}

#define GP_MMA(MQ, NQ, BF)                                                              \
    __builtin_amdgcn_s_barrier();                                                       \
    __builtin_amdgcn_s_setprio(1);                                                      \
    _Pragma("unroll") for (int m = 0; m < 4; m++)                                       \
        _Pragma("unroll") for (int n = 0; n < 2; n++)                                   \
            _Pragma("unroll") for (int s = 0; s < 2; s++)                               \
                acc[(MQ) * 4 + m][(NQ) * 2 + n] = __builtin_amdgcn_mfma_f32_16x16x32_f16( \
                    af[m][s], (BF)[n][s], acc[(MQ) * 4 + m][(NQ) * 2 + n], 0, 0, 0);    \
    __builtin_amdgcn_s_setprio(0);                                                      \
    __builtin_amdgcn_s_barrier();

template <typename OutT>
__global__ __launch_bounds__(512, 2) void gemm256(const _Float16* __restrict__ A,
                                                  const _Float16* __restrict__ BT,
                                                  OutT* __restrict__ C,
                                                  int M, int N, int K) {
    __shared__ __align__(16) _Float16 smem[4 * 16384];   // 128 KiB: A0,A1,B0,B1
    _Float16* const AsBase = smem;
    _Float16* const BsBase = smem + 32768;

    const int tid = threadIdx.x;
    const int wid = tid >> 6, lane = tid & 63;
    const int wm = wid >> 2, wn = wid & 3;               // 2 x 4 waves
    const int fr = lane & 15, q = lane >> 4, frq = fr & 7;
    const int sw0 = (q ^ frq) << 3;                      // kk=0 swizzled chunk offset
    const int sw1 = ((4 + q) ^ frq) << 3;                // kk=1
    const int aB0 = (wm * 64 + fr) * 64;                 // mq0 fragment row base
    const int bB0 = (wn * 32 + fr) * 64;                 // nq0 fragment row base

    // XCD-chunked bijective swizzle: dispatch slot lin runs on XCD lin%8;
    // give each XCD a contiguous range of logical ids -> 8 full A-row-panels.
    int lin = blockIdx.y * gridDim.x + blockIdx.x;
    const int nwg = gridDim.x * gridDim.y;               // multiple of 8 here
    lin = (lin & 7) * (nwg >> 3) + (lin >> 3);
    const int bx = lin % gridDim.x, by = lin / gridDim.x;
    const int row0 = by * 256, col0 = bx * 256;
    const int NT = K >> 6;

    floatx4 acc[8][4] = {};
    half8 af[4][2], bf0[2][2], bf1[2][2];

    // Prologue: tile0 fully + tile1 {A-h0, B-h0}; gate leaves tile1 halves in flight.
    stage_half(A,  K, row0,       0, AsBase);            // t0 A-h0
    stage_half(BT, K, col0,       0, BsBase);            // t0 B-h0
    stage_half(A,  K, row0 + 128, 0, AsBase + 8192);     // t0 A-h1
    stage_half(BT, K, col0 + 128, 0, BsBase + 8192);     // t0 B-h1
    if (NT > 1) {
        stage_half(A,  K, row0, 64, AsBase + 16384);     // t1 A-h0
        stage_half(BT, K, col0, 64, BsBase + 16384);     // t1 B-h0
        asm volatile("s_waitcnt vmcnt(4)" ::: "memory");
    } else {
        asm volatile("s_waitcnt vmcnt(0)" ::: "memory");
    }
    __builtin_amdgcn_s_barrier();
    loadB4(bf0, BsBase, bB0, sw0, sw1);                  // t0 nq0 (all waves gated+barriered)

    for (int t = 0; t < NT; ++t) {
        _Float16* Ab  = AsBase + ((t & 1) << 14);
        _Float16* Bb  = BsBase + ((t & 1) << 14);
        _Float16* Abn = AsBase + (((t + 1) & 1) << 14);
        _Float16* Bbn = BsBase + (((t + 1) & 1) << 14);
        const int k1 = (t + 1) << 6, k2 = (t + 2) << 6;
        const bool s1 = (t + 1) < NT, s2 = (t + 2) < NT;

        // p0: q00 (af<-mq0 in-phase, bf0 pipelined from p3(t-1)); read bf1 for p1
        loadA8(af, Ab, aB0, sw0, sw1);
        loadB4(bf1, Bb, bB0 + 8192, sw0, sw1);
        if (s1) stage_half(A, K, row0 + 128, k1, Abn + 8192);
        GP_MMA(0, 0, bf0);

        // p1: q01 (af live, bf1 drained under q00)
        if (s1) stage_half(BT, K, col0 + 128, k1, Bbn + 8192);
        GP_MMA(0, 1, bf1);

        // p2: q10 (af<-mq1 in-phase, bf0 live)
        loadA8(af, Ab, aB0 + 8192, sw0, sw1);
        if (s2) stage_half(A, K, row0, k2, Ab);
        GP_MMA(1, 0, bf0);

        // p3: stage; gate; barrier (all-wave landing of t+1); read next bf0; q11
        if (s2) stage_half(BT, K, col0, k2, Bb);
        if (s2) {
            asm volatile("s_waitcnt vmcnt(4)" ::: "memory");
        } else if (t + 2 == NT) {
            asm volatile("s_waitcnt vmcnt(0)" ::: "memory");
        }
        __builtin_amdgcn_s_barrier();
        loadB4(bf0, Bbn, bB0, sw0, sw1);                 // next tile q00 operand
        GP_MMA(1, 1, bf1);
    }

    // C/D layout: col = lane&15, row = (lane>>4)*4 + reg   [measured m89/m91]
    const int er = (lane >> 4) * 4, ec = lane & 15;
#pragma unroll
    for (int fi = 0; fi < 8; fi++)
#pragma unroll
        for (int fj = 0; fj < 4; fj++)
#pragma unroll
            for (int r = 0; r < 4; r++) {
                int row = row0 + (fi >> 2) * 128 + wm * 64 + (fi & 3) * 16 + er + r;
                int col = col0 + (fj >> 1) * 128 + wn * 32 + (fj & 1) * 16 + ec;
                C[(size_t)row * N + col] = (OutT)acc[fi][fj][r];
            }
}

// ---------------- fused conv + silu + Bt/Ct (MFMA) + scan p1 ----------------
// Block = 32 rows (2 chunks), 256 threads = 4 waves. Waves own disjoint K
// quarters (512 cols = 4 panels of 128) -> NO barriers in the main loop.
__global__ __launch_bounds__(256) void conv_bc_fin(const _Float16* __restrict__ xr,
                                                   const float* __restrict__ cw,
                                                   const float* __restrict__ cb,
                                                   const _Float16* __restrict__ WBCT,
                                                   const float* __restrict__ A,
                                                   _Float16* __restrict__ xc,
                                                   float* __restrict__ BtCt,
                                                   float* __restrict__ fin) {
    __shared__ __align__(16) _Float16 As[4 * 32 * 128];   // 32 KB; reused in epilogue
    const int tid = threadIdx.x, wid = tid >> 6, lane = tid & 63;
    const int row0 = blockIdx.x * 32;
    const int l0 = row0 & (SEQ - 1);
    const int cg = lane & 15;            // col-group within panel (8 cols)
    const int rg = lane >> 4;            // row-group (8 rows)
    const int fr = lane & 15, q = lane >> 4;
    _Float16* As_w = As + wid * 4096;
    const int r0 = rg * 8;

    floatx4 acc[2][2] = {};

    for (int t = 0; t < 4; t++) {
        const int kbase = wid * 512 + t * 128;
        const int gcol = kbase + cg * 8;
        float w0[8], w1[8], w2[8], bb[8];
#pragma unroll
        for (int j = 0; j < 8; j++) {
            w0[j] = cw[(gcol + j) * 3];
            w1[j] = cw[(gcol + j) * 3 + 1];
            w2[j] = cw[(gcol + j) * 3 + 2];
            bb[j] = cb[gcol + j];
        }
        half8 prev = {}, cur, nxt;
        if (!(l0 == 0 && rg == 0))
            prev = *(const half8*)(xr + (size_t)(row0 + r0 - 1) * 4096 + gcol);
        cur = *(const half8*)(xr + (size_t)(row0 + r0) * 4096 + gcol);
#pragma unroll
        for (int r = 0; r < 8; r++) {
            if (r == 7 && rg == 3 && l0 + 32 == SEQ) {
                half8 z = {};
                nxt = z;
            } else {
                nxt = *(const half8*)(xr + (size_t)(row0 + r0 + r + 1) * 4096 + gcol);
            }
            half8 o;
#pragma unroll
            for (int j = 0; j < 8; j++) {
                float a = (float)prev[j] * w0[j] + (float)cur[j] * w1[j] +
                          (float)nxt[j] * w2[j] + bb[j];
                o[j] = (_Float16)siluf(a);
            }
            const int lrow = r0 + r;
            *(half8*)(xc + (size_t)(row0 + lrow) * D_INNER + gcol) = o;
            *(half8*)(As_w + lrow * 128 + ((cg ^ (lrow & 7)) * 8)) = o;
            prev = cur;
            cur = nxt;
        }
#pragma unroll
        for (int ks = 0; ks < 4; ks++) {
            half8 af[2], bf[2];
#pragma unroll
            for (int rt = 0; rt < 2; rt++)
                af[rt] = *(const half8*)(As_w + (rt * 16 + fr) * 128 +
                                         (((ks * 4 + q) ^ (fr & 7)) * 8));
#pragma unroll
            for (int ot = 0; ot < 2; ot++)
                bf[ot] = *(const half8*)(WBCT + (size_t)(ot * 16 + fr) * D_INNER +
                                         kbase + ks * 32 + q * 8);
#pragma unroll
            for (int rt = 0; rt < 2; rt++)
#pragma unroll
                for (int ot = 0; ot < 2; ot++)
                    acc[rt][ot] = __builtin_amdgcn_mfma_f32_16x16x32_f16(af[rt], bf[ot], acc[rt][ot], 0, 0, 0);
        }
    }

    __syncthreads();                       // all waves done reading As as f16
    float* red = (float*)As;               // [wid][row 32][out 32] = 4096 f32 (16 KB)
    float* btl = (float*)As + 4096;        // [row 32][out 32] = 1024 f32 (4 KB)
    const int er = (lane >> 4) * 4, ec = lane & 15;
#pragma unroll
    for (int rt = 0; rt < 2; rt++)
#pragma unroll
        for (int ot = 0; ot < 2; ot++)
#pragma unroll
            for (int rr = 0; rr < 4; rr++)
                red[wid * 1024 + (rt * 16 + er + rr) * 32 + ot * 16 + ec] = acc[rt][ot][rr];
    __syncthreads();
#pragma unroll
    for (int i = 0; i < 4; i++) {
        int idx = i * 256 + tid;           // (row<<5)|out
        float v = red[idx] + red[1024 + idx] + red[2048 + idx] + red[3072 + idx];
        btl[idx] = v;
        BtCt[(size_t)row0 * 32 + idx] = v; // (row0+row)*32+out == row0*32+idx
    }
    __syncthreads();
    if (tid < 32) {                        // 2 chunks x 16 states
        const int ch = tid >> 4, s = tid & 15;
        const float decay = decay_of(A, s);
        float st = 0.f;
#pragma unroll
        for (int r = 0; r < CHUNK; r++)
            st = st * decay + btl[(ch * 16 + r) * 32 + s];
        fin[((row0 >> 4) + ch) * 16 + s] = st;
    }
}

// -------------------------------- scan -------------------------------------
// phase 2: carry propagation across chunks. 1 block x 64 threads (b,s).
__global__ __launch_bounds__(64) void scan_p2(const float* __restrict__ fin,
                                              const float* __restrict__ A,
                                              float* __restrict__ carry) {
    int t = threadIdx.x;
    int b = t >> 4, s = t & 15;
    float decay = decay_of(A, s);
    float d16 = decay;
#pragma unroll
    for (int k = 0; k < 4; k++) d16 *= d16;     // decay^16
    float cy = 0.f;
#pragma unroll 8
    for (int c = 0; c < NCHUNK; c++) {
        int idx = ((b * NCHUNK) + c) * 16 + s;
        carry[idx] = cy;
        cy = cy * d16 + fin[idx];
    }
}

// phase 3 + y-fuse: replay chunk scan (lanes 0..15, Bt/Ct preloaded to regs)
// -> ys in LDS, then all 256 threads compute y = (ys + xc*D) * silu(res),
// overwriting xc (f16). 1024 blocks x 256 threads; block = chunk-task.
__global__ __launch_bounds__(256) void scan_p3_fuse(const float* __restrict__ BtCt,
                                                    const float* __restrict__ A,
                                                    const float* __restrict__ carry,
                                                    const float* __restrict__ D,
                                                    const _Float16* __restrict__ xr,
                                                    _Float16* __restrict__ xc) {
    __shared__ float ysl[CHUNK];
    const int task = blockIdx.x;
    const int b = task >> 8, c = task & (NCHUNK - 1);
    const int row0 = b * SEQ + c * CHUNK;
    const int tid = threadIdx.x;

    if (tid < 16) {
        const int s = tid;
        const float decay = decay_of(A, s);
        size_t r = (size_t)row0 * 32;
        float bt[CHUNK], ct[CHUNK];
#pragma unroll
        for (int j = 0; j < CHUNK; j++) {       // independent loads, ILP
            bt[j] = BtCt[r + (size_t)j * 32 + s];
            ct[j] = BtCt[r + (size_t)j * 32 + 16 + s];
        }
        float st = carry[task * 16 + s];
        float yv[CHUNK];
#pragma unroll
        for (int j = 0; j < CHUNK; j++) {       // serial FMA chain only
            st = st * decay + bt[j];
            yv[j] = st * ct[j];
        }
#pragma unroll
        for (int j = 0; j < CHUNK; j++) {       // 16 independent reduce chains
            float y = yv[j];
            y += __shfl_xor(y, 1, 16);
            y += __shfl_xor(y, 2, 16);
            y += __shfl_xor(y, 4, 16);
            y += __shfl_xor(y, 8, 16);
            if (s == 0) ysl[j] = y;
        }
    }
    __syncthreads();

#pragma unroll
    for (int it = 0; it < 16; it++) {
        int chunk = it * 256 + tid;            // 0..4095 (16 rows x 256 col-chunks)
        int rl = chunk >> 8;                   // row within chunk
        int colb = (chunk & 255) * 8;          // col offset (elements)
        size_t row = (size_t)(row0 + rl);
        float yv = ysl[rl];
        half8 x8 = *(const half8*)(xc + row * D_INNER + colb);
        half8 r8 = *(const half8*)(xr + row * 4096 + 2048 + colb);
        float4 d0 = *(const float4*)(D + colb);
        float4 d1 = *(const float4*)(D + colb + 4);
        half8 o;
        float dd[8] = {d0.x, d0.y, d0.z, d0.w, d1.x, d1.y, d1.z, d1.w};
#pragma unroll
        for (int j = 0; j < 8; j++) {
            float y = yv + (float)x8[j] * dd[j];
            o[j] = (_Float16)(y * siluf((float)r8[j]));
        }
        *(half8*)(xc + row * D_INNER + colb) = o;
    }
}

// ------------------------------- launcher ----------------------------------
extern "C" void kernel_launch(void* const* d_in, const int* in_sizes, int n_in,
                              void* d_out, int out_size, void* d_ws, size_t ws_size,
                              hipStream_t stream) {
    const float* x      = (const float*)d_in[0];
    const float* W_in   = (const float*)d_in[1];
    const float* conv_w = (const float*)d_in[2];
    const float* conv_b = (const float*)d_in[3];
    const float* W_B    = (const float*)d_in[4];
    const float* W_C    = (const float*)d_in[5];
    const float* A      = (const float*)d_in[6];
    const float* D      = (const float*)d_in[7];
    const float* W_out  = (const float*)d_in[8];
    float* out = (float*)d_out;

    char* ws = (char*)d_ws;
    size_t off = 0;
    auto alloc = [&](size_t bytes) { size_t o = off; off += (bytes + 255) & ~(size_t)255; return o; };
    _Float16* xh    = (_Float16*)(ws + alloc((size_t)NROWS * D_MODEL * 2));      // 33.5 MB
    _Float16* WinT  = (_Float16*)(ws + alloc((size_t)4096 * 1024 * 2));          //  8.4 MB
    _Float16* WoutT = (_Float16*)(ws + alloc((size_t)1024 * 2048 * 2));          //  4.2 MB
    _Float16* WBCT  = (_Float16*)(ws + alloc((size_t)32 * 2048 * 2));            //  0.13 MB
    _Float16* xr    = (_Float16*)(ws + alloc((size_t)NROWS * 4096 * 2));         //  134 MB
    _Float16* xc    = (_Float16*)(ws + alloc((size_t)NROWS * D_INNER * 2));      //   67 MB
    float*    BtCt  = (float*)(ws + alloc((size_t)NROWS * 32 * 4));              //    2 MB
    float*    fin   = (float*)(ws + alloc((size_t)NTASK * 16 * 4));              //  64 KB
    float*    carry = (float*)(ws + alloc((size_t)NTASK * 16 * 4));              //  64 KB

    // 1. conversions
    convert_f32_f16<<<(NROWS * D_MODEL) / (256 * 8), 256, 0, stream>>>(x, xh);
    transpose_to_f16<<<dim3(4096 / 32, 1024 / 32), dim3(32, 8), 0, stream>>>(W_in, WinT, 1024, 4096);
    transpose_to_f16<<<dim3(1024 / 32, 2048 / 32), dim3(32, 8), 0, stream>>>(W_out, WoutT, 2048, 1024);
    convert_wbct<<<(32 * 2048) / 256, 256, 0, stream>>>(W_B, W_C, WBCT);
    // 2. GEMM1: xr = x @ W_in   (16384x4096x1024), 8-phase 256^2
    gemm256<_Float16><<<dim3(4096 / 256, NROWS / 256), 512, 0, stream>>>(xh, WinT, xr, NROWS, 4096, 1024);
    // 3. conv + silu + Bt/Ct + fin (fused, MFMA)
    conv_bc_fin<<<NROWS / 32, 256, 0, stream>>>(xr, conv_w, conv_b, WBCT, A, xc, BtCt, fin);
    // 4. scan phase 2
    scan_p2<<<1, 64, 0, stream>>>(fin, A, carry);
    // 5. scan phase 3 + y-fuse
    scan_p3_fuse<<<NTASK, 256, 0, stream>>>(BtCt, A, carry, D, xr, xc);
    // 6. GEMM2: out = y @ W_out (16384x1024x2048), 8-phase 256^2
    gemm256<float><<<dim3(1024 / 256, NROWS / 256), 512, 0, stream>>>(xc, WoutT, out, NROWS, 1024, 2048);
}